// Round 10
// baseline (198.576 us; speedup 1.0000x reference)
//
#include <hip/hip_runtime.h>
#include <hip/hip_bf16.h>

// MHA fwd: B=2, S=2048, D=1024, H=16, HD=64. fp32 in/out, bf16 MFMA internals.
// R20: (1) qkv reverted to R10 2-barrier structure (R19 dbuf regressed:
// MfmaUtil 24->22 — TLP already covered the drain; m99/m100 reproduced).
// (2) cast_x FUSED into gemm_qkv: A-side reg-staged from fp32 X
// (2x float4 -> cvt -> ds_write_b128, dest chunk (lane&7)^(r8&7) =
// conflict-free, As content bit-identical to glds layout). Cast kernel and
// its 16 MB HBM round-trip deleted. (3) attn: T5 setprio(1) around MFMA
// clusters (m191: +4-7% on attn).
// attn core: R17 32x32x16 in-register-P (correct, verified R8).

typedef __bf16 bf16x8 __attribute__((ext_vector_type(8)));
typedef __bf16 bf16x4 __attribute__((ext_vector_type(4)));
typedef __bf16 bf16x2 __attribute__((ext_vector_type(2)));
typedef float f32x4 __attribute__((ext_vector_type(4)));
typedef float f32x16 __attribute__((ext_vector_type(16)));
typedef unsigned int u32x4 __attribute__((ext_vector_type(4)));

#define S_LEN 2048
#define DMODEL 1024
#define NHEAD 16
#define HDIM 64
#define MROWS 4096  // B*S

#define AS1 __attribute__((address_space(1)))
#define AS3 __attribute__((address_space(3)))

#define QSCALE 0.18033688f  // 0.125 * log2e: scores come out in log2 units

// ------------- transpose + cast all 4 weights: WT[n][k] = W[k][n] -------------
__global__ void transpose_cast_kernel(
    const float* __restrict__ W0, const float* __restrict__ W1,
    const float* __restrict__ W2, const float* __restrict__ W3,
    __bf16* __restrict__ T0, __bf16* __restrict__ T1,
    __bf16* __restrict__ T2, __bf16* __restrict__ T3) {
    const float* W = (blockIdx.z == 0) ? W0 : (blockIdx.z == 1) ? W1 : (blockIdx.z == 2) ? W2 : W3;
    __bf16* WT = (blockIdx.z == 0) ? T0 : (blockIdx.z == 1) ? T1 : (blockIdx.z == 2) ? T2 : T3;
    __shared__ float tile[32][33];
    int bx = blockIdx.x, by = blockIdx.y;
    int tx = threadIdx.x;
    for (int i = threadIdx.y; i < 32; i += 8)
        tile[i][tx] = W[(size_t)(by * 32 + i) * DMODEL + bx * 32 + tx];
    __syncthreads();
    for (int i = threadIdx.y; i < 32; i += 8)
        WT[(size_t)(bx * 32 + i) * DMODEL + by * 32 + tx] = (__bf16)tile[tx][i];
}

// ------------- GEMM QKV: 128x64 tile, BK=64 (R10 structure) ------------------
// A-side: reg-staged from fp32 X. Lane: row r8=lane>>3, source col (lane&7)*8
// (linear, coalesced), LDS dest chunk ((lane&7)^(r8&7)) — bank-conflict-free,
// reproduces the glds XOR layout As[r][c]=X[r][c^(r&7)]. B-side: glds 16B.
__global__ __launch_bounds__(256) void gemm_qkv_kernel(
    const float* __restrict__ X,
    const __bf16* __restrict__ WqT, const __bf16* __restrict__ WkT, const __bf16* __restrict__ WvT,
    const float* __restrict__ bq, const float* __restrict__ bk, const float* __restrict__ bv,
    __bf16* __restrict__ Q, __bf16* __restrict__ K, __bf16* __restrict__ Vt) {
    const int which = blockIdx.z;
    const __bf16* Bt = (which == 0) ? WqT : (which == 1) ? WkT : WvT;
    const float* bias = (which == 0) ? bq : (which == 1) ? bk : bv;
    __bf16* Out = (which == 0) ? Q : (which == 1) ? K : Vt;

    __shared__ alignas(16) __bf16 As[128 * 64];
    __shared__ alignas(16) __bf16 Bs[64 * 64];

    const int tid = threadIdx.x;
    const int lane = tid & 63;
    const int wave = tid >> 6;
    const int wm = wave >> 1, wn = wave & 1;
    const int quad = lane >> 4;
    const int l16 = lane & 15;
    const int m0 = blockIdx.x * 128;   // m-tile on x (XCD locality)
    const int n0 = blockIdx.y * 64;
    const int r8 = lane >> 3;
    const int sc8 = ((lane & 7) ^ r8) * 8;          // B glds source swizzle
    const int a_src = (lane & 7) * 8;                // A fp32 source col (linear)
    const int a_dst = ((lane & 7) ^ (r8 & 7)) * 8;   // A LDS dest chunk (swz)
    const int gq0 = ((0 + quad) ^ (l16 & 7)) * 8;
    const int gq1 = ((4 + quad) ^ (l16 & 7)) * 8;

    f32x4 acc[4][2] = {};

    for (int k0 = 0; k0 < DMODEL; k0 += 64) {
        __syncthreads();
        // A: 128 rows fp32 -> cvt -> LDS (reg-staged, fused x-cast)
#pragma unroll
        for (int p = 0; p < 4; p++) {
            const int row = wave * 32 + p * 8 + r8;
            const float* src = &X[(size_t)(m0 + row) * DMODEL + k0 + a_src];
            float4 f0 = *(const float4*)(src);
            float4 f1 = *(const float4*)(src + 4);
            bf16x8 v;
            v[0] = (__bf16)f0.x; v[1] = (__bf16)f0.y;
            v[2] = (__bf16)f0.z; v[3] = (__bf16)f0.w;
            v[4] = (__bf16)f1.x; v[5] = (__bf16)f1.y;
            v[6] = (__bf16)f1.z; v[7] = (__bf16)f1.w;
            *(bf16x8*)&As[row * 64 + a_dst] = v;
        }
        // B: 64 rows bf16 via glds
#pragma unroll
        for (int p = 0; p < 2; p++) {
            const int row = wave * 16 + p * 8;
            __builtin_amdgcn_global_load_lds(
                (const AS1 void*)&Bt[(size_t)(n0 + row + r8) * DMODEL + k0 + sc8],
                (AS3 void*)&Bs[row * 64], 16, 0, 0);
        }
        __syncthreads();
#pragma unroll
        for (int ks = 0; ks < 2; ks++) {
            const int g = ks ? gq1 : gq0;
            bf16x8 af[4], bfr[2];
#pragma unroll
            for (int t = 0; t < 4; t++)
                af[t] = *(bf16x8*)&As[(wm * 64 + t * 16 + l16) * 64 + g];
#pragma unroll
            for (int t = 0; t < 2; t++)
                bfr[t] = *(bf16x8*)&Bs[(wn * 32 + t * 16 + l16) * 64 + g];
#pragma unroll
            for (int mt = 0; mt < 4; mt++)
#pragma unroll
                for (int nt = 0; nt < 2; nt++)
                    acc[mt][nt] = __builtin_amdgcn_mfma_f32_16x16x32_bf16(af[mt], bfr[nt], acc[mt][nt], 0, 0, 0);
        }
    }

    // C/D layout: col = lane&15, row = quad*4 + reg  [m89-verified]
#pragma unroll
    for (int mt = 0; mt < 4; mt++)
#pragma unroll
        for (int nt = 0; nt < 2; nt++) {
            const int n = n0 + wn * 32 + nt * 16 + l16;
            const float bn = bias[n];
            const int h = n >> 6, hd = n & 63;
            const int mbase = m0 + wm * 64 + mt * 16 + quad * 4;
            if (which == 2) {
                __bf16 pk[4];
#pragma unroll
                for (int r = 0; r < 4; r++) pk[r] = (__bf16)(acc[mt][nt][r] + bn);
                const int m = mbase;
                const int b = m >> 11, s = m & 2047;
                *(uint2*)&Out[(((size_t)(b * NHEAD + h) * HDIM + hd) * S_LEN) + s] = *(uint2*)pk;
            } else {
                const float sc = (which == 0) ? QSCALE : 1.0f;  // Q: fold 1/8 * log2e
#pragma unroll
                for (int r = 0; r < 4; r++) {
                    const int m = mbase + r;
                    const int b = m >> 11, s = m & 2047;
                    Out[(((size_t)(b * NHEAD + h) * S_LEN + s) * HDIM) + hd] =
                        (__bf16)((acc[mt][nt][r] + bn) * sc);
                }
            }
        }
}

// ------------- GEMM OUT: 64x64 tile, BK=64, grid (64,16): m-tile on x --------
__global__ __launch_bounds__(256) void gemm_out_kernel(
    const __bf16* __restrict__ A, const __bf16* __restrict__ Bt,
    const float* __restrict__ bias, float* __restrict__ Y) {
    __shared__ alignas(16) __bf16 As[64 * 64];
    __shared__ alignas(16) __bf16 Bs[64 * 64];

    const int tid = threadIdx.x;
    const int lane = tid & 63;
    const int wave = tid >> 6;
    const int wm = wave >> 1, wn = wave & 1;
    const int quad = lane >> 4;
    const int l16 = lane & 15;
    const int m0 = blockIdx.x * 64;    // m-tile on x (XCD locality)
    const int n0 = blockIdx.y * 64;
    const int r8 = lane >> 3;
    const int sc8 = ((lane & 7) ^ r8) * 8;
    const int gq0 = ((0 + quad) ^ (l16 & 7)) * 8;
    const int gq1 = ((4 + quad) ^ (l16 & 7)) * 8;

    f32x4 acc[2][2] = {};

    for (int k0 = 0; k0 < DMODEL; k0 += 64) {
        __syncthreads();
#pragma unroll
        for (int p = 0; p < 2; p++) {
            const int row = wave * 16 + p * 8;
            __builtin_amdgcn_global_load_lds(
                (const AS1 void*)&A[(size_t)(m0 + row + r8) * DMODEL + k0 + sc8],
                (AS3 void*)&As[row * 64], 16, 0, 0);
            __builtin_amdgcn_global_load_lds(
                (const AS1 void*)&Bt[(size_t)(n0 + row + r8) * DMODEL + k0 + sc8],
                (AS3 void*)&Bs[row * 64], 16, 0, 0);
        }
        __syncthreads();
#pragma unroll
        for (int ks = 0; ks < 2; ks++) {
            const int g = ks ? gq1 : gq0;
            bf16x8 af[2], bfr[2];
#pragma unroll
            for (int t = 0; t < 2; t++) {
                af[t]  = *(bf16x8*)&As[(wm * 32 + t * 16 + l16) * 64 + g];
                bfr[t] = *(bf16x8*)&Bs[(wn * 32 + t * 16 + l16) * 64 + g];
            }
#pragma unroll
            for (int mt = 0; mt < 2; mt++)
#pragma unroll
                for (int nt = 0; nt < 2; nt++)
                    acc[mt][nt] = __builtin_amdgcn_mfma_f32_16x16x32_bf16(af[mt], bfr[nt], acc[mt][nt], 0, 0, 0);
        }
    }

#pragma unroll
    for (int mt = 0; mt < 2; mt++)
#pragma unroll
        for (int nt = 0; nt < 2; nt++)
#pragma unroll
            for (int r = 0; r < 4; r++) {
                int m = m0 + wm * 32 + mt * 16 + quad * 4 + r;
                int n = n0 + wn * 32 + nt * 16 + l16;
                Y[(size_t)m * DMODEL + n] = acc[mt][nt][r] + bias[n];
            }
}

// -------- flash attention (R17 core + R20 setprio) ---------------------------
// Ks[128 k][64 hd] (chunk ^= row&7), Vs[64 hd][128 k] (chunk ^= hd&15).
// Wave (wq,wk): 32 q-rows x 64 k-cols. Swapped QK: sacc = mfma(K,Q) = S^T,
// lane = q-col (lane&31), 16 k-rows via (r&3)+8*(r>>2)+4*(lane>>5).
// PA frags assembled via bf16-pack + shfl_xor(32). O += mfma(PA, V);
// l += mfma(PA, ones). V chunks offset by k-half (kl0>>3).
// setprio(1) wraps the QK and PV MFMA clusters (T5, m191).

static __device__ __forceinline__ unsigned pkbf2(float a, float b) {
    bf16x2 t;
    t[0] = (__bf16)a;
    t[1] = (__bf16)b;
    return __builtin_bit_cast(unsigned, t);
}

template <bool MASK>
__device__ __forceinline__ void attn_tile32(
    const __bf16* Ks, const __bf16* Vs,
    const bf16x8 (&qf)[4], const bf16x8& onesf,
    f32x16 (&oacc)[2], f32x16& lacc,
    int q_lane, int kl0, int kabs0, int lane) {
    const int l32 = lane & 31, hi = lane >> 5, l7 = lane & 7, l15 = lane & 15;
    const int cbase = kl0 >> 3;   // wave's V chunk base (0 or 8)
    bf16x8 pa[4];
#pragma unroll
    for (int sub = 0; sub < 2; sub++) {
        f32x16 s = {};
        const int row = kl0 + sub * 32 + l32;
        __builtin_amdgcn_s_setprio(1);
#pragma unroll
        for (int j = 0; j < 4; j++) {
            const int ch = ((2 * j + hi) ^ l7) * 8;
            bf16x8 kf = *(const bf16x8*)&Ks[row * 64 + ch];
            s = __builtin_amdgcn_mfma_f32_32x32x16_bf16(kf, qf[j], s, 0, 0, 0);
        }
        __builtin_amdgcn_s_setprio(0);
        float p[16];
#pragma unroll
        for (int r = 0; r < 16; r++) {
            const float e = __builtin_amdgcn_exp2f(s[r]);
            if (MASK) {
                const int kabs = kabs0 + sub * 32 + (r & 3) + 8 * (r >> 2) + 4 * hi;
                p[r] = (kabs > q_lane) ? 0.0f : e;
            } else {
                p[r] = e;
            }
        }
        const unsigned c0 = pkbf2(p[0], p[1]),   c1 = pkbf2(p[2], p[3]);
        const unsigned c2 = pkbf2(p[4], p[5]),   c3 = pkbf2(p[6], p[7]);
        const unsigned c4 = pkbf2(p[8], p[9]),   c5 = pkbf2(p[10], p[11]);
        const unsigned c6 = pkbf2(p[12], p[13]), c7 = pkbf2(p[14], p[15]);
        const unsigned sA0 = hi ? c0 : c2, sA1 = hi ? c1 : c3;
        const unsigned rA0 = __shfl_xor(sA0, 32, 64), rA1 = __shfl_xor(sA1, 32, 64);
        const unsigned sB0 = hi ? c4 : c6, sB1 = hi ? c5 : c7;
        const unsigned rB0 = __shfl_xor(sB0, 32, 64), rB1 = __shfl_xor(sB1, 32, 64);
        u32x4 wA, wB;
        if (hi) {
            wA[0] = rA0; wA[1] = rA1; wA[2] = c2; wA[3] = c3;
            wB[0] = rB0; wB[1] = rB1; wB[2] = c6; wB[3] = c7;
        } else {
            wA[0] = c0; wA[1] = c1; wA[2] = rA0; wA[3] = rA1;
            wB[0] = c4; wB[1] = c5; wB[2] = rB0; wB[3] = rB1;
        }
        pa[sub * 2]     = __builtin_bit_cast(bf16x8, wA);
        pa[sub * 2 + 1] = __builtin_bit_cast(bf16x8, wB);
    }
    __builtin_amdgcn_s_setprio(1);
#pragma unroll
    for (int kblk = 0; kblk < 4; kblk++) {
#pragma unroll
        for (int dsub = 0; dsub < 2; dsub++) {
            const int hd = dsub * 32 + l32;
            const int ch = ((cbase + kblk * 2 + hi) ^ l15) * 8;
            bf16x8 vf = *(const bf16x8*)&Vs[hd * 128 + ch];
            oacc[dsub] = __builtin_amdgcn_mfma_f32_32x32x16_bf16(pa[kblk], vf, oacc[dsub], 0, 0, 0);
        }
        lacc = __builtin_amdgcn_mfma_f32_32x32x16_bf16(pa[kblk], onesf, lacc, 0, 0, 0);
    }
    __builtin_amdgcn_s_setprio(0);
}

__global__ __launch_bounds__(256, 3) void attn_kernel(
    const __bf16* __restrict__ Q, const __bf16* __restrict__ K, const __bf16* __restrict__ Vt,
    __bf16* __restrict__ Aout) {
    const int id = blockIdx.x;
    const int bh = id & 31;                 // XCD-pinned: id%8 == bh%8
    const int qt = 31 - (id >> 5);          // big tiles first
    const int b = bh >> 4, h = bh & 15;
    const int tid = threadIdx.x, lane = tid & 63, wave = tid >> 6;
    const int wq = wave >> 1, wk = wave & 1;
    const int l32 = lane & 31, hi = lane >> 5;

    __shared__ alignas(16) __bf16 SMEM[128 * 64 + 64 * 128];  // Ks | Vs (32 KB)
    __bf16* Ks = SMEM;
    __bf16* Vs = SMEM + 128 * 64;

    const size_t base = (size_t)bh * S_LEN * HDIM;   // same for Q, K, Vt
    const int q0 = qt * 64;
    const int q_lane = q0 + wq * 32 + l32;

    bf16x8 qf[4];
#pragma unroll
    for (int j = 0; j < 4; j++)
        qf[j] = *(const bf16x8*)&Q[base + (size_t)q_lane * HDIM + j * 16 + hi * 8];

    bf16x8 onesf;
#pragma unroll
    for (int jj = 0; jj < 8; jj++) onesf[jj] = (__bf16)1.0f;

    f32x16 oacc[2] = {};
    f32x16 lacc = {};

    // staging lane roles
    const int r8k = lane >> 3;
    const int sck = ((lane & 7) ^ r8k) * 8;   // K source chunk (elems)
    const int r4v = lane >> 4;                // V: 4 rows per glds

    const int kb_all = (qt >> 1) + 1;
    const int kl0 = wk * 64;                  // this wave's local k base

    for (int kb = 0; kb < kb_all; kb++) {
        const int k0 = kb * 128;
        __syncthreads();
#pragma unroll
        for (int p = 0; p < 4; p++) {  // K: 128 rows, 8 rows/glds
            const int row = wave * 32 + p * 8;
            __builtin_amdgcn_global_load_lds(
                (const AS1 void*)&K[base + (size_t)(k0 + row + r8k) * HDIM + sck],
                (AS3 void*)&Ks[row * 64], 16, 0, 0);
        }
#pragma unroll
        for (int p = 0; p < 4; p++) {  // V^T: 64 rows x 128 cols, 4 rows/glds
            const int row = wave * 16 + p * 4;
            const int lc = ((lane & 15) ^ ((p * 4 + r4v) & 15)) * 8;
            __builtin_amdgcn_global_load_lds(
                (const AS1 void*)&Vt[base + (size_t)(row + r4v) * S_LEN + k0 + lc],
                (AS3 void*)&Vs[row * 128], 16, 0, 0);
        }
        __syncthreads();

        if (kb == kb_all - 1)
            attn_tile32<true>(Ks, Vs, qf, onesf, oacc, lacc, q_lane, kl0, k0 + kl0, lane);
        else
            attn_tile32<false>(Ks, Vs, qf, onesf, oacc, lacc, q_lane, kl0, k0 + kl0, lane);
    }

    // ---- k-half reduction via LDS scratch (stride 49 f32: conflict-free) ----
    __syncthreads();
    float* scr = (float*)SMEM;
    const int slot = (wq * 64 + lane) * 49;
    if (wk) {
#pragma unroll
        for (int ss = 0; ss < 2; ss++)
#pragma unroll
            for (int r = 0; r < 16; r++) scr[slot + ss * 16 + r] = oacc[ss][r];
#pragma unroll
        for (int r = 0; r < 16; r++) scr[slot + 32 + r] = lacc[r];
    }
    __syncthreads();
    if (!wk) {
#pragma unroll
        for (int ss = 0; ss < 2; ss++)
#pragma unroll
            for (int r = 0; r < 16; r++) oacc[ss][r] += scr[slot + ss * 16 + r];
#pragma unroll
        for (int r = 0; r < 16; r++) lacc[r] += scr[slot + 32 + r];
        float rl[16];
#pragma unroll
        for (int r = 0; r < 16; r++) rl[r] = 1.0f / lacc[r];
#pragma unroll
        for (int ss = 0; ss < 2; ss++)
#pragma unroll
            for (int r = 0; r < 16; r++) {
                const int q = q0 + wq * 32 + (r & 3) + 8 * (r >> 2) + 4 * hi;
                Aout[(size_t)(b * S_LEN + q) * DMODEL + h * 64 + ss * 32 + l32] =
                    (__bf16)(oacc[ss][r] * rl[r]);
            }
    }
}

extern "C" void kernel_launch(void* const* d_in, const int* in_sizes, int n_in,
                              void* d_out, int out_size, void* d_ws, size_t ws_size,
                              hipStream_t stream) {
    const float* x  = (const float*)d_in[0];
    // d_in[1] = mask: causal triu, reproduced analytically
    const float* wq = (const float*)d_in[2];
    const float* bq = (const float*)d_in[3];
    const float* wk = (const float*)d_in[4];
    const float* bk = (const float*)d_in[5];
    const float* wv = (const float*)d_in[6];
    const float* bv = (const float*)d_in[7];
    const float* wo = (const float*)d_in[8];
    const float* bo = (const float*)d_in[9];
    float* out = (float*)d_out;

    char* ws = (char*)d_ws;
    __bf16* wqT = (__bf16*)(ws + ((size_t)8  << 20));     // 2 MiB each
    __bf16* wkT = (__bf16*)(ws + ((size_t)10 << 20));
    __bf16* wvT = (__bf16*)(ws + ((size_t)12 << 20));
    __bf16* woT = (__bf16*)(ws + ((size_t)14 << 20));
    __bf16* Qb  = (__bf16*)(ws + ((size_t)16 << 20));     // 8 MiB each
    __bf16* Kb  = (__bf16*)(ws + ((size_t)24 << 20));
    __bf16* Vtb = (__bf16*)(ws + ((size_t)32 << 20));     // V^T [B,H,HD,S]
    __bf16* Ab  = (__bf16*)(ws + ((size_t)40 << 20));     // 8 MiB

    transpose_cast_kernel<<<dim3(32, 32, 4), dim3(32, 8), 0, stream>>>(
        wq, wk, wv, wo, wqT, wkT, wvT, woT);
    gemm_qkv_kernel<<<dim3(32, 16, 3), 256, 0, stream>>>(x, wqT, wkT, wvT, bq, bk, bv, Qb, Kb, Vtb);
    attn_kernel<<<1024, 256, 0, stream>>>(Qb, Kb, Vtb, Ab);
    gemm_out_kernel<<<dim3(64, 16), 256, 0, stream>>>(Ab, woT, bo, out);
}

// Round 11
// 196.793 us; speedup vs baseline: 1.0091x; 1.0091x over previous
//
#include <hip/hip_runtime.h>
#include <hip/hip_bf16.h>

// MHA fwd: B=2, S=2048, D=1024, H=16, HD=64. fp32 in/out, bf16 MFMA internals.
// R21 = R8 (best verified, 183.6us) + ONE change: attn V-staging dropped
// (catalog common-mistake #7: don't LDS-stage L2-resident data — per-XCD V
// working set ~2MB < 4MB L2). V read direct from global as 8 independent
// 16B/lane loads per wave per tile (same lane->element mapping, un-swizzled),
// hoistable above softmax; K staging via glds unchanged. Vs LDS deleted
// (SMEM = max(Ks 16KB, epilogue scratch 25KB)).
// R20's cast-fusion REVERTED (qkv 40.8->61.9: reg-staged fp32 A serialized
// load->cvt->ds_write in the barrier window; glds restored + cast_x kernel).
// setprio dropped (R20 residual suggests null in barriered attn, cf. m190).
// qkv/out/cast/transpose identical to R8.

typedef __bf16 bf16x8 __attribute__((ext_vector_type(8)));
typedef __bf16 bf16x4 __attribute__((ext_vector_type(4)));
typedef __bf16 bf16x2 __attribute__((ext_vector_type(2)));
typedef float f32x4 __attribute__((ext_vector_type(4)));
typedef float f32x16 __attribute__((ext_vector_type(16)));
typedef unsigned int u32x4 __attribute__((ext_vector_type(4)));

#define S_LEN 2048
#define DMODEL 1024
#define NHEAD 16
#define HDIM 64
#define MROWS 4096  // B*S

#define AS1 __attribute__((address_space(1)))
#define AS3 __attribute__((address_space(3)))

#define QSCALE 0.18033688f  // 0.125 * log2e: scores come out in log2 units

// ---------------- cast x (fp32 -> bf16), 4 elems/thread ----------------
__global__ void cast_x_kernel(const float* __restrict__ X, __bf16* __restrict__ Xb) {
    int i = (blockIdx.x * blockDim.x + threadIdx.x) * 4;
    float4 f = *(const float4*)&X[i];
    Xb[i + 0] = (__bf16)f.x;
    Xb[i + 1] = (__bf16)f.y;
    Xb[i + 2] = (__bf16)f.z;
    Xb[i + 3] = (__bf16)f.w;
}

// ------------- transpose + cast all 4 weights: WT[n][k] = W[k][n] -------------
__global__ void transpose_cast_kernel(
    const float* __restrict__ W0, const float* __restrict__ W1,
    const float* __restrict__ W2, const float* __restrict__ W3,
    __bf16* __restrict__ T0, __bf16* __restrict__ T1,
    __bf16* __restrict__ T2, __bf16* __restrict__ T3) {
    const float* W = (blockIdx.z == 0) ? W0 : (blockIdx.z == 1) ? W1 : (blockIdx.z == 2) ? W2 : W3;
    __bf16* WT = (blockIdx.z == 0) ? T0 : (blockIdx.z == 1) ? T1 : (blockIdx.z == 2) ? T2 : T3;
    __shared__ float tile[32][33];
    int bx = blockIdx.x, by = blockIdx.y;
    int tx = threadIdx.x;
    for (int i = threadIdx.y; i < 32; i += 8)
        tile[i][tx] = W[(size_t)(by * 32 + i) * DMODEL + bx * 32 + tx];
    __syncthreads();
    for (int i = threadIdx.y; i < 32; i += 8)
        WT[(size_t)(bx * 32 + i) * DMODEL + by * 32 + tx] = (__bf16)tile[tx][i];
}

// ------------- GEMM QKV: 128x64 tile, BK=64, glds(16B) + XOR swizzle ---------
__global__ __launch_bounds__(256) void gemm_qkv_kernel(
    const __bf16* __restrict__ X,
    const __bf16* __restrict__ WqT, const __bf16* __restrict__ WkT, const __bf16* __restrict__ WvT,
    const float* __restrict__ bq, const float* __restrict__ bk, const float* __restrict__ bv,
    __bf16* __restrict__ Q, __bf16* __restrict__ K, __bf16* __restrict__ Vt) {
    const int which = blockIdx.z;
    const __bf16* Bt = (which == 0) ? WqT : (which == 1) ? WkT : WvT;
    const float* bias = (which == 0) ? bq : (which == 1) ? bk : bv;
    __bf16* Out = (which == 0) ? Q : (which == 1) ? K : Vt;

    __shared__ alignas(16) __bf16 As[128 * 64];
    __shared__ alignas(16) __bf16 Bs[64 * 64];

    const int tid = threadIdx.x;
    const int lane = tid & 63;
    const int wave = tid >> 6;
    const int wm = wave >> 1, wn = wave & 1;
    const int quad = lane >> 4;
    const int l16 = lane & 15;
    const int m0 = blockIdx.x * 128;   // m-tile on x (XCD locality)
    const int n0 = blockIdx.y * 64;
    const int r8 = lane >> 3;
    const int sc8 = ((lane & 7) ^ r8) * 8;
    const int gq0 = ((0 + quad) ^ (l16 & 7)) * 8;
    const int gq1 = ((4 + quad) ^ (l16 & 7)) * 8;

    f32x4 acc[4][2] = {};

    for (int k0 = 0; k0 < DMODEL; k0 += 64) {
        __syncthreads();
#pragma unroll
        for (int p = 0; p < 4; p++) {  // A: 128 rows
            const int row = wave * 32 + p * 8;
            __builtin_amdgcn_global_load_lds(
                (const AS1 void*)&X[(size_t)(m0 + row + r8) * DMODEL + k0 + sc8],
                (AS3 void*)&As[row * 64], 16, 0, 0);
        }
#pragma unroll
        for (int p = 0; p < 2; p++) {  // B: 64 rows
            const int row = wave * 16 + p * 8;
            __builtin_amdgcn_global_load_lds(
                (const AS1 void*)&Bt[(size_t)(n0 + row + r8) * DMODEL + k0 + sc8],
                (AS3 void*)&Bs[row * 64], 16, 0, 0);
        }
        __syncthreads();
#pragma unroll
        for (int ks = 0; ks < 2; ks++) {
            const int g = ks ? gq1 : gq0;
            bf16x8 af[4], bfr[2];
#pragma unroll
            for (int t = 0; t < 4; t++)
                af[t] = *(bf16x8*)&As[(wm * 64 + t * 16 + l16) * 64 + g];
#pragma unroll
            for (int t = 0; t < 2; t++)
                bfr[t] = *(bf16x8*)&Bs[(wn * 32 + t * 16 + l16) * 64 + g];
#pragma unroll
            for (int mt = 0; mt < 4; mt++)
#pragma unroll
                for (int nt = 0; nt < 2; nt++)
                    acc[mt][nt] = __builtin_amdgcn_mfma_f32_16x16x32_bf16(af[mt], bfr[nt], acc[mt][nt], 0, 0, 0);
        }
    }

    // C/D layout: col = lane&15, row = quad*4 + reg  [m89-verified]
#pragma unroll
    for (int mt = 0; mt < 4; mt++)
#pragma unroll
        for (int nt = 0; nt < 2; nt++) {
            const int n = n0 + wn * 32 + nt * 16 + l16;
            const float bn = bias[n];
            const int h = n >> 6, hd = n & 63;
            const int mbase = m0 + wm * 64 + mt * 16 + quad * 4;
            if (which == 2) {
                __bf16 pk[4];
#pragma unroll
                for (int r = 0; r < 4; r++) pk[r] = (__bf16)(acc[mt][nt][r] + bn);
                const int m = mbase;
                const int b = m >> 11, s = m & 2047;
                *(uint2*)&Out[(((size_t)(b * NHEAD + h) * HDIM + hd) * S_LEN) + s] = *(uint2*)pk;
            } else {
                const float sc = (which == 0) ? QSCALE : 1.0f;  // Q: fold 1/8 * log2e
#pragma unroll
                for (int r = 0; r < 4; r++) {
                    const int m = mbase + r;
                    const int b = m >> 11, s = m & 2047;
                    Out[(((size_t)(b * NHEAD + h) * S_LEN + s) * HDIM) + hd] =
                        (__bf16)((acc[mt][nt][r] + bn) * sc);
                }
            }
        }
}

// ------------- GEMM OUT: 64x64 tile, BK=64, grid (64,16): m-tile on x --------
__global__ __launch_bounds__(256) void gemm_out_kernel(
    const __bf16* __restrict__ A, const __bf16* __restrict__ Bt,
    const float* __restrict__ bias, float* __restrict__ Y) {
    __shared__ alignas(16) __bf16 As[64 * 64];
    __shared__ alignas(16) __bf16 Bs[64 * 64];

    const int tid = threadIdx.x;
    const int lane = tid & 63;
    const int wave = tid >> 6;
    const int wm = wave >> 1, wn = wave & 1;
    const int quad = lane >> 4;
    const int l16 = lane & 15;
    const int m0 = blockIdx.x * 64;    // m-tile on x (XCD locality)
    const int n0 = blockIdx.y * 64;
    const int r8 = lane >> 3;
    const int sc8 = ((lane & 7) ^ r8) * 8;
    const int gq0 = ((0 + quad) ^ (l16 & 7)) * 8;
    const int gq1 = ((4 + quad) ^ (l16 & 7)) * 8;

    f32x4 acc[2][2] = {};

    for (int k0 = 0; k0 < DMODEL; k0 += 64) {
        __syncthreads();
#pragma unroll
        for (int p = 0; p < 2; p++) {
            const int row = wave * 16 + p * 8;
            __builtin_amdgcn_global_load_lds(
                (const AS1 void*)&A[(size_t)(m0 + row + r8) * DMODEL + k0 + sc8],
                (AS3 void*)&As[row * 64], 16, 0, 0);
            __builtin_amdgcn_global_load_lds(
                (const AS1 void*)&Bt[(size_t)(n0 + row + r8) * DMODEL + k0 + sc8],
                (AS3 void*)&Bs[row * 64], 16, 0, 0);
        }
        __syncthreads();
#pragma unroll
        for (int ks = 0; ks < 2; ks++) {
            const int g = ks ? gq1 : gq0;
            bf16x8 af[2], bfr[2];
#pragma unroll
            for (int t = 0; t < 2; t++) {
                af[t]  = *(bf16x8*)&As[(wm * 32 + t * 16 + l16) * 64 + g];
                bfr[t] = *(bf16x8*)&Bs[(wn * 32 + t * 16 + l16) * 64 + g];
            }
#pragma unroll
            for (int mt = 0; mt < 2; mt++)
#pragma unroll
                for (int nt = 0; nt < 2; nt++)
                    acc[mt][nt] = __builtin_amdgcn_mfma_f32_16x16x32_bf16(af[mt], bfr[nt], acc[mt][nt], 0, 0, 0);
        }
    }

#pragma unroll
    for (int mt = 0; mt < 2; mt++)
#pragma unroll
        for (int nt = 0; nt < 2; nt++)
#pragma unroll
            for (int r = 0; r < 4; r++) {
                int m = m0 + wm * 32 + mt * 16 + quad * 4 + r;
                int n = n0 + wn * 32 + nt * 16 + l16;
                Y[(size_t)m * DMODEL + n] = acc[mt][nt][r] + bias[n];
            }
}

// -------- flash attention (R21: 32x32x16, in-register P, V direct from L2) ---
// Ks[128 k][64 hd] LDS (chunk ^= row&7). V NOT staged: vf = 16B/lane direct
// global read Vt[hd][kabs0 + kblk*16 + hi*8] — same lane->element mapping the
// LDS path produced. Wave (wq,wk): 32 q x 64 k. Swapped QK: sacc = mfma(K,Q),
// lane = q-col (lane&31), k-rows (r&3)+8*(r>>2)+4*hi. PA via bf16-pack +
// shfl_xor(32). O += mfma(PA,V); l += mfma(PA,ones).
// Epilogue: k-half partials reduced via LDS scratch (stride 49 f32, 25KB).

static __device__ __forceinline__ unsigned pkbf2(float a, float b) {
    bf16x2 t;
    t[0] = (__bf16)a;
    t[1] = (__bf16)b;
    return __builtin_bit_cast(unsigned, t);
}

template <bool MASK>
__device__ __forceinline__ void attn_tile32(
    const __bf16* Ks, const __bf16* __restrict__ Vg,
    const bf16x8 (&qf)[4], const bf16x8& onesf,
    f32x16 (&oacc)[2], f32x16& lacc,
    int q_lane, int kl0, int kabs0, int lane) {
    const int l32 = lane & 31, hi = lane >> 5, l7 = lane & 7;
    bf16x8 pa[4];
#pragma unroll
    for (int sub = 0; sub < 2; sub++) {
        f32x16 s = {};
        const int row = kl0 + sub * 32 + l32;
#pragma unroll
        for (int j = 0; j < 4; j++) {
            const int ch = ((2 * j + hi) ^ l7) * 8;
            bf16x8 kf = *(const bf16x8*)&Ks[row * 64 + ch];
            s = __builtin_amdgcn_mfma_f32_32x32x16_bf16(kf, qf[j], s, 0, 0, 0);
        }
        float p[16];
#pragma unroll
        for (int r = 0; r < 16; r++) {
            const float e = __builtin_amdgcn_exp2f(s[r]);
            if (MASK) {
                const int kabs = kabs0 + sub * 32 + (r & 3) + 8 * (r >> 2) + 4 * hi;
                p[r] = (kabs > q_lane) ? 0.0f : e;
            } else {
                p[r] = e;
            }
        }
        const unsigned c0 = pkbf2(p[0], p[1]),   c1 = pkbf2(p[2], p[3]);
        const unsigned c2 = pkbf2(p[4], p[5]),   c3 = pkbf2(p[6], p[7]);
        const unsigned c4 = pkbf2(p[8], p[9]),   c5 = pkbf2(p[10], p[11]);
        const unsigned c6 = pkbf2(p[12], p[13]), c7 = pkbf2(p[14], p[15]);
        const unsigned sA0 = hi ? c0 : c2, sA1 = hi ? c1 : c3;
        const unsigned rA0 = __shfl_xor(sA0, 32, 64), rA1 = __shfl_xor(sA1, 32, 64);
        const unsigned sB0 = hi ? c4 : c6, sB1 = hi ? c5 : c7;
        const unsigned rB0 = __shfl_xor(sB0, 32, 64), rB1 = __shfl_xor(sB1, 32, 64);
        u32x4 wA, wB;
        if (hi) {
            wA[0] = rA0; wA[1] = rA1; wA[2] = c2; wA[3] = c3;
            wB[0] = rB0; wB[1] = rB1; wB[2] = c6; wB[3] = c7;
        } else {
            wA[0] = c0; wA[1] = c1; wA[2] = rA0; wA[3] = rA1;
            wB[0] = c4; wB[1] = c5; wB[2] = rB0; wB[3] = rB1;
        }
        pa[sub * 2]     = __builtin_bit_cast(bf16x8, wA);
        pa[sub * 2 + 1] = __builtin_bit_cast(bf16x8, wB);
    }
#pragma unroll
    for (int kblk = 0; kblk < 4; kblk++) {
#pragma unroll
        for (int dsub = 0; dsub < 2; dsub++) {
            const int hd = dsub * 32 + l32;
            bf16x8 vf = *(const bf16x8*)&Vg[(size_t)hd * S_LEN + kabs0 + kblk * 16 + hi * 8];
            oacc[dsub] = __builtin_amdgcn_mfma_f32_32x32x16_bf16(pa[kblk], vf, oacc[dsub], 0, 0, 0);
        }
        lacc = __builtin_amdgcn_mfma_f32_32x32x16_bf16(pa[kblk], onesf, lacc, 0, 0, 0);
    }
}

__global__ __launch_bounds__(256, 3) void attn_kernel(
    const __bf16* __restrict__ Q, const __bf16* __restrict__ K, const __bf16* __restrict__ Vt,
    __bf16* __restrict__ Aout) {
    const int id = blockIdx.x;
    const int bh = id & 31;                 // XCD-pinned: id%8 == bh%8
    const int qt = 31 - (id >> 5);          // big tiles first
    const int b = bh >> 4, h = bh & 15;
    const int tid = threadIdx.x, lane = tid & 63, wave = tid >> 6;
    const int wq = wave >> 1, wk = wave & 1;
    const int l32 = lane & 31, hi = lane >> 5;

    // LDS: Ks (16 KB) and epilogue scratch (25 KB) share one allocation
    __shared__ alignas(16) float SCR[6272];
    __bf16* Ks = (__bf16*)SCR;

    const size_t base = (size_t)bh * S_LEN * HDIM;   // same for Q, K, Vt
    const __bf16* Vg = Vt + base;
    const int q0 = qt * 64;
    const int q_lane = q0 + wq * 32 + l32;

    bf16x8 qf[4];
#pragma unroll
    for (int j = 0; j < 4; j++)
        qf[j] = *(const bf16x8*)&Q[base + (size_t)q_lane * HDIM + j * 16 + hi * 8];

    bf16x8 onesf;
#pragma unroll
    for (int jj = 0; jj < 8; jj++) onesf[jj] = (__bf16)1.0f;

    f32x16 oacc[2] = {};
    f32x16 lacc = {};

    // staging lane roles (K only)
    const int r8k = lane >> 3;
    const int sck = ((lane & 7) ^ r8k) * 8;   // K source chunk (elems)

    const int kb_all = (qt >> 1) + 1;
    const int kl0 = wk * 64;                  // this wave's local k base

    for (int kb = 0; kb < kb_all; kb++) {
        const int k0 = kb * 128;
        __syncthreads();
#pragma unroll
        for (int p = 0; p < 4; p++) {  // K: 128 rows, 8 rows/glds
            const int row = wave * 32 + p * 8;
            __builtin_amdgcn_global_load_lds(
                (const AS1 void*)&K[base + (size_t)(k0 + row + r8k) * HDIM + sck],
                (AS3 void*)&Ks[row * 64], 16, 0, 0);
        }
        __syncthreads();

        if (kb == kb_all - 1)
            attn_tile32<true>(Ks, Vg, qf, onesf, oacc, lacc, q_lane, kl0, k0 + kl0, lane);
        else
            attn_tile32<false>(Ks, Vg, qf, onesf, oacc, lacc, q_lane, kl0, k0 + kl0, lane);
    }

    // ---- k-half reduction via LDS scratch (stride 49 f32: conflict-free) ----
    __syncthreads();
    float* scr = SCR;
    const int slot = (wq * 64 + lane) * 49;
    if (wk) {
#pragma unroll
        for (int ss = 0; ss < 2; ss++)
#pragma unroll
            for (int r = 0; r < 16; r++) scr[slot + ss * 16 + r] = oacc[ss][r];
#pragma unroll
        for (int r = 0; r < 16; r++) scr[slot + 32 + r] = lacc[r];
    }
    __syncthreads();
    if (!wk) {
#pragma unroll
        for (int ss = 0; ss < 2; ss++)
#pragma unroll
            for (int r = 0; r < 16; r++) oacc[ss][r] += scr[slot + ss * 16 + r];
#pragma unroll
        for (int r = 0; r < 16; r++) lacc[r] += scr[slot + 32 + r];
        float rl[16];
#pragma unroll
        for (int r = 0; r < 16; r++) rl[r] = 1.0f / lacc[r];
#pragma unroll
        for (int ss = 0; ss < 2; ss++)
#pragma unroll
            for (int r = 0; r < 16; r++) {
                const int q = q0 + wq * 32 + (r & 3) + 8 * (r >> 2) + 4 * hi;
                Aout[(size_t)(b * S_LEN + q) * DMODEL + h * 64 + ss * 32 + l32] =
                    (__bf16)(oacc[ss][r] * rl[r]);
            }
    }
}

extern "C" void kernel_launch(void* const* d_in, const int* in_sizes, int n_in,
                              void* d_out, int out_size, void* d_ws, size_t ws_size,
                              hipStream_t stream) {
    const float* x  = (const float*)d_in[0];
    // d_in[1] = mask: causal triu, reproduced analytically
    const float* wq = (const float*)d_in[2];
    const float* bq = (const float*)d_in[3];
    const float* wk = (const float*)d_in[4];
    const float* bk = (const float*)d_in[5];
    const float* wv = (const float*)d_in[6];
    const float* bv = (const float*)d_in[7];
    const float* wo = (const float*)d_in[8];
    const float* bo = (const float*)d_in[9];
    float* out = (float*)d_out;

    char* ws = (char*)d_ws;
    __bf16* xb  = (__bf16*)(ws);                          // 8 MiB
    __bf16* wqT = (__bf16*)(ws + ((size_t)8  << 20));     // 2 MiB each
    __bf16* wkT = (__bf16*)(ws + ((size_t)10 << 20));
    __bf16* wvT = (__bf16*)(ws + ((size_t)12 << 20));
    __bf16* woT = (__bf16*)(ws + ((size_t)14 << 20));
    __bf16* Qb  = (__bf16*)(ws + ((size_t)16 << 20));     // 8 MiB each
    __bf16* Kb  = (__bf16*)(ws + ((size_t)24 << 20));
    __bf16* Vtb = (__bf16*)(ws + ((size_t)32 << 20));     // V^T [B,H,HD,S]
    __bf16* Ab  = (__bf16*)(ws + ((size_t)40 << 20));     // 8 MiB

    cast_x_kernel<<<4096, 256, 0, stream>>>(x, xb);
    transpose_cast_kernel<<<dim3(32, 32, 4), dim3(32, 8), 0, stream>>>(
        wq, wk, wv, wo, wqT, wkT, wvT, woT);
    gemm_qkv_kernel<<<dim3(32, 16, 3), 256, 0, stream>>>(xb, wqT, wkT, wvT, bq, bk, bv, Qb, Kb, Vtb);
    attn_kernel<<<1024, 256, 0, stream>>>(Qb, Kb, Vtb, Ab);
    gemm_out_kernel<<<dim3(64, 16), 256, 0, stream>>>(Ab, woT, bo, out);
}

// Round 12
// 186.180 us; speedup vs baseline: 1.0666x; 1.0570x over previous
//
#include <hip/hip_runtime.h>
#include <hip/hip_bf16.h>

// MHA fwd: B=2, S=2048, D=1024, H=16, HD=64. fp32 in/out, bf16 MFMA internals.
// R22 = R8 + ONE structural change: gemm_qkv fused across Q/K/V outputs.
// Old: grid (32,16,3), each z re-stages the same X panel (3x A-traffic,
// 24576 barrier-instances). New: grid (64,16), one block computes 64x64 for
// ALL THREE outputs from one As stage: 8 glds / 24 MFMA per K-step per wave
// (was 6/16), barrier-instances 16384, FETCH ideal 31->14MB. LDS 32KB.
// R21's V-direct REVERTED (attn 38->51: per-lane hd-strided V reads are a
// 64-line gather on the PV critical path; glds V restored).
// attn: R8/R17 exact (32x32x16, in-register P, Vs LDS, no setprio).

typedef __bf16 bf16x8 __attribute__((ext_vector_type(8)));
typedef __bf16 bf16x4 __attribute__((ext_vector_type(4)));
typedef __bf16 bf16x2 __attribute__((ext_vector_type(2)));
typedef float f32x4 __attribute__((ext_vector_type(4)));
typedef float f32x16 __attribute__((ext_vector_type(16)));
typedef unsigned int u32x4 __attribute__((ext_vector_type(4)));

#define S_LEN 2048
#define DMODEL 1024
#define NHEAD 16
#define HDIM 64
#define MROWS 4096  // B*S

#define AS1 __attribute__((address_space(1)))
#define AS3 __attribute__((address_space(3)))

#define QSCALE 0.18033688f  // 0.125 * log2e: scores come out in log2 units

// ---------------- cast x (fp32 -> bf16), 4 elems/thread ----------------
__global__ void cast_x_kernel(const float* __restrict__ X, __bf16* __restrict__ Xb) {
    int i = (blockIdx.x * blockDim.x + threadIdx.x) * 4;
    float4 f = *(const float4*)&X[i];
    Xb[i + 0] = (__bf16)f.x;
    Xb[i + 1] = (__bf16)f.y;
    Xb[i + 2] = (__bf16)f.z;
    Xb[i + 3] = (__bf16)f.w;
}

// ------------- transpose + cast all 4 weights: WT[n][k] = W[k][n] -------------
__global__ void transpose_cast_kernel(
    const float* __restrict__ W0, const float* __restrict__ W1,
    const float* __restrict__ W2, const float* __restrict__ W3,
    __bf16* __restrict__ T0, __bf16* __restrict__ T1,
    __bf16* __restrict__ T2, __bf16* __restrict__ T3) {
    const float* W = (blockIdx.z == 0) ? W0 : (blockIdx.z == 1) ? W1 : (blockIdx.z == 2) ? W2 : W3;
    __bf16* WT = (blockIdx.z == 0) ? T0 : (blockIdx.z == 1) ? T1 : (blockIdx.z == 2) ? T2 : T3;
    __shared__ float tile[32][33];
    int bx = blockIdx.x, by = blockIdx.y;
    int tx = threadIdx.x;
    for (int i = threadIdx.y; i < 32; i += 8)
        tile[i][tx] = W[(size_t)(by * 32 + i) * DMODEL + bx * 32 + tx];
    __syncthreads();
    for (int i = threadIdx.y; i < 32; i += 8)
        WT[(size_t)(bx * 32 + i) * DMODEL + by * 32 + tx] = (__bf16)tile[tx][i];
}

// ------------- GEMM QKV fused: 64x64 tile x 3 outputs, BK=64 -----------------
// One As stage feeds Q, K, V MFMA chains: 2+6 glds, 24 MFMA per K-step/wave.
__global__ __launch_bounds__(256) void gemm_qkv_kernel(
    const __bf16* __restrict__ X,
    const __bf16* __restrict__ WqT, const __bf16* __restrict__ WkT, const __bf16* __restrict__ WvT,
    const float* __restrict__ bq, const float* __restrict__ bk, const float* __restrict__ bv,
    __bf16* __restrict__ Q, __bf16* __restrict__ K, __bf16* __restrict__ Vt) {
    __shared__ alignas(16) __bf16 As[64 * 64];
    __shared__ alignas(16) __bf16 Bs[3][64 * 64];

    const int tid = threadIdx.x;
    const int lane = tid & 63;
    const int wave = tid >> 6;
    const int wm = wave >> 1, wn = wave & 1;
    const int quad = lane >> 4;
    const int l16 = lane & 15;
    const int m0 = blockIdx.x * 64;    // m-tile on x (XCD locality)
    const int n0 = blockIdx.y * 64;
    const int r8 = lane >> 3;
    const int sc8 = ((lane & 7) ^ r8) * 8;
    const int gq0 = ((0 + quad) ^ (l16 & 7)) * 8;
    const int gq1 = ((4 + quad) ^ (l16 & 7)) * 8;

    const __bf16* Bts[3] = {WqT, WkT, WvT};

    f32x4 acc[3][2][2] = {};

    for (int k0 = 0; k0 < DMODEL; k0 += 64) {
        __syncthreads();
#pragma unroll
        for (int p = 0; p < 2; p++) {
            const int row = wave * 16 + p * 8;
            __builtin_amdgcn_global_load_lds(
                (const AS1 void*)&X[(size_t)(m0 + row + r8) * DMODEL + k0 + sc8],
                (AS3 void*)&As[row * 64], 16, 0, 0);
#pragma unroll
            for (int w = 0; w < 3; w++)
                __builtin_amdgcn_global_load_lds(
                    (const AS1 void*)&Bts[w][(size_t)(n0 + row + r8) * DMODEL + k0 + sc8],
                    (AS3 void*)&Bs[w][row * 64], 16, 0, 0);
        }
        __syncthreads();
#pragma unroll
        for (int ks = 0; ks < 2; ks++) {
            const int g = ks ? gq1 : gq0;
            bf16x8 af[2];
#pragma unroll
            for (int t = 0; t < 2; t++)
                af[t] = *(bf16x8*)&As[(wm * 32 + t * 16 + l16) * 64 + g];
#pragma unroll
            for (int w = 0; w < 3; w++) {
                bf16x8 bfr[2];
#pragma unroll
                for (int t = 0; t < 2; t++)
                    bfr[t] = *(bf16x8*)&Bs[w][(wn * 32 + t * 16 + l16) * 64 + g];
#pragma unroll
                for (int mt = 0; mt < 2; mt++)
#pragma unroll
                    for (int nt = 0; nt < 2; nt++)
                        acc[w][mt][nt] = __builtin_amdgcn_mfma_f32_16x16x32_bf16(
                            af[mt], bfr[nt], acc[w][mt][nt], 0, 0, 0);
            }
        }
    }

    // C/D layout: col = lane&15, row = quad*4 + reg  [m89-verified]
#pragma unroll
    for (int w = 0; w < 3; w++) {
        const float* bias = (w == 0) ? bq : (w == 1) ? bk : bv;
        __bf16* Out = (w == 0) ? Q : (w == 1) ? K : Vt;
#pragma unroll
        for (int mt = 0; mt < 2; mt++)
#pragma unroll
            for (int nt = 0; nt < 2; nt++) {
                const int n = n0 + wn * 32 + nt * 16 + l16;
                const float bn = bias[n];
                const int h = n >> 6, hd = n & 63;
                const int mbase = m0 + wm * 32 + mt * 16 + quad * 4;
                if (w == 2) {
                    __bf16 pk[4];
#pragma unroll
                    for (int r = 0; r < 4; r++) pk[r] = (__bf16)(acc[w][mt][nt][r] + bn);
                    const int m = mbase;
                    const int b = m >> 11, s = m & 2047;
                    *(uint2*)&Out[(((size_t)(b * NHEAD + h) * HDIM + hd) * S_LEN) + s] = *(uint2*)pk;
                } else {
                    const float sc = (w == 0) ? QSCALE : 1.0f;  // Q: fold 1/8 * log2e
#pragma unroll
                    for (int r = 0; r < 4; r++) {
                        const int m = mbase + r;
                        const int b = m >> 11, s = m & 2047;
                        Out[(((size_t)(b * NHEAD + h) * S_LEN + s) * HDIM) + hd] =
                            (__bf16)((acc[w][mt][nt][r] + bn) * sc);
                    }
                }
            }
    }
}

// ------------- GEMM OUT: 64x64 tile, BK=64, grid (64,16): m-tile on x --------
__global__ __launch_bounds__(256) void gemm_out_kernel(
    const __bf16* __restrict__ A, const __bf16* __restrict__ Bt,
    const float* __restrict__ bias, float* __restrict__ Y) {
    __shared__ alignas(16) __bf16 As[64 * 64];
    __shared__ alignas(16) __bf16 Bs[64 * 64];

    const int tid = threadIdx.x;
    const int lane = tid & 63;
    const int wave = tid >> 6;
    const int wm = wave >> 1, wn = wave & 1;
    const int quad = lane >> 4;
    const int l16 = lane & 15;
    const int m0 = blockIdx.x * 64;    // m-tile on x (XCD locality)
    const int n0 = blockIdx.y * 64;
    const int r8 = lane >> 3;
    const int sc8 = ((lane & 7) ^ r8) * 8;
    const int gq0 = ((0 + quad) ^ (l16 & 7)) * 8;
    const int gq1 = ((4 + quad) ^ (l16 & 7)) * 8;

    f32x4 acc[2][2] = {};

    for (int k0 = 0; k0 < DMODEL; k0 += 64) {
        __syncthreads();
#pragma unroll
        for (int p = 0; p < 2; p++) {
            const int row = wave * 16 + p * 8;
            __builtin_amdgcn_global_load_lds(
                (const AS1 void*)&A[(size_t)(m0 + row + r8) * DMODEL + k0 + sc8],
                (AS3 void*)&As[row * 64], 16, 0, 0);
            __builtin_amdgcn_global_load_lds(
                (const AS1 void*)&Bt[(size_t)(n0 + row + r8) * DMODEL + k0 + sc8],
                (AS3 void*)&Bs[row * 64], 16, 0, 0);
        }
        __syncthreads();
#pragma unroll
        for (int ks = 0; ks < 2; ks++) {
            const int g = ks ? gq1 : gq0;
            bf16x8 af[2], bfr[2];
#pragma unroll
            for (int t = 0; t < 2; t++) {
                af[t]  = *(bf16x8*)&As[(wm * 32 + t * 16 + l16) * 64 + g];
                bfr[t] = *(bf16x8*)&Bs[(wn * 32 + t * 16 + l16) * 64 + g];
            }
#pragma unroll
            for (int mt = 0; mt < 2; mt++)
#pragma unroll
                for (int nt = 0; nt < 2; nt++)
                    acc[mt][nt] = __builtin_amdgcn_mfma_f32_16x16x32_bf16(af[mt], bfr[nt], acc[mt][nt], 0, 0, 0);
        }
    }

#pragma unroll
    for (int mt = 0; mt < 2; mt++)
#pragma unroll
        for (int nt = 0; nt < 2; nt++)
#pragma unroll
            for (int r = 0; r < 4; r++) {
                int m = m0 + wm * 32 + mt * 16 + quad * 4 + r;
                int n = n0 + wn * 32 + nt * 16 + l16;
                Y[(size_t)m * DMODEL + n] = acc[mt][nt][r] + bias[n];
            }
}

// -------- flash attention (R8/R17: 32x32x16 MFMA, in-register P) -------------
// Ks[128 k][64 hd] (chunk ^= row&7), Vs[64 hd][128 k] (chunk ^= hd&15).
// Wave (wq,wk): 32 q-rows x 64 k-cols. Swapped QK: sacc = mfma(K,Q) = S^T,
// lane = q-col (lane&31), 16 k-rows via (r&3)+8*(r>>2)+4*(lane>>5).
// PA frags assembled via bf16-pack + shfl_xor(32). O += mfma(PA, V);
// l += mfma(PA, ones). V chunks offset by k-half (kl0>>3).
// Epilogue: k-half partials reduced via LDS scratch (stride 49 f32).

static __device__ __forceinline__ unsigned pkbf2(float a, float b) {
    bf16x2 t;
    t[0] = (__bf16)a;
    t[1] = (__bf16)b;
    return __builtin_bit_cast(unsigned, t);
}

template <bool MASK>
__device__ __forceinline__ void attn_tile32(
    const __bf16* Ks, const __bf16* Vs,
    const bf16x8 (&qf)[4], const bf16x8& onesf,
    f32x16 (&oacc)[2], f32x16& lacc,
    int q_lane, int kl0, int kabs0, int lane) {
    const int l32 = lane & 31, hi = lane >> 5, l7 = lane & 7, l15 = lane & 15;
    const int cbase = kl0 >> 3;   // wave's V chunk base (0 or 8)
    bf16x8 pa[4];
#pragma unroll
    for (int sub = 0; sub < 2; sub++) {
        f32x16 s = {};
        const int row = kl0 + sub * 32 + l32;
#pragma unroll
        for (int j = 0; j < 4; j++) {
            const int ch = ((2 * j + hi) ^ l7) * 8;
            bf16x8 kf = *(const bf16x8*)&Ks[row * 64 + ch];
            s = __builtin_amdgcn_mfma_f32_32x32x16_bf16(kf, qf[j], s, 0, 0, 0);
        }
        float p[16];
#pragma unroll
        for (int r = 0; r < 16; r++) {
            const float e = __builtin_amdgcn_exp2f(s[r]);
            if (MASK) {
                const int kabs = kabs0 + sub * 32 + (r & 3) + 8 * (r >> 2) + 4 * hi;
                p[r] = (kabs > q_lane) ? 0.0f : e;
            } else {
                p[r] = e;
            }
        }
        const unsigned c0 = pkbf2(p[0], p[1]),   c1 = pkbf2(p[2], p[3]);
        const unsigned c2 = pkbf2(p[4], p[5]),   c3 = pkbf2(p[6], p[7]);
        const unsigned c4 = pkbf2(p[8], p[9]),   c5 = pkbf2(p[10], p[11]);
        const unsigned c6 = pkbf2(p[12], p[13]), c7 = pkbf2(p[14], p[15]);
        const unsigned sA0 = hi ? c0 : c2, sA1 = hi ? c1 : c3;
        const unsigned rA0 = __shfl_xor(sA0, 32, 64), rA1 = __shfl_xor(sA1, 32, 64);
        const unsigned sB0 = hi ? c4 : c6, sB1 = hi ? c5 : c7;
        const unsigned rB0 = __shfl_xor(sB0, 32, 64), rB1 = __shfl_xor(sB1, 32, 64);
        u32x4 wA, wB;
        if (hi) {
            wA[0] = rA0; wA[1] = rA1; wA[2] = c2; wA[3] = c3;
            wB[0] = rB0; wB[1] = rB1; wB[2] = c6; wB[3] = c7;
        } else {
            wA[0] = c0; wA[1] = c1; wA[2] = rA0; wA[3] = rA1;
            wB[0] = c4; wB[1] = c5; wB[2] = rB0; wB[3] = rB1;
        }
        pa[sub * 2]     = __builtin_bit_cast(bf16x8, wA);
        pa[sub * 2 + 1] = __builtin_bit_cast(bf16x8, wB);
    }
#pragma unroll
    for (int kblk = 0; kblk < 4; kblk++) {
#pragma unroll
        for (int dsub = 0; dsub < 2; dsub++) {
            const int hd = dsub * 32 + l32;
            const int ch = ((cbase + kblk * 2 + hi) ^ l15) * 8;
            bf16x8 vf = *(const bf16x8*)&Vs[hd * 128 + ch];
            oacc[dsub] = __builtin_amdgcn_mfma_f32_32x32x16_bf16(pa[kblk], vf, oacc[dsub], 0, 0, 0);
        }
        lacc = __builtin_amdgcn_mfma_f32_32x32x16_bf16(pa[kblk], onesf, lacc, 0, 0, 0);
    }
}

__global__ __launch_bounds__(256, 3) void attn_kernel(
    const __bf16* __restrict__ Q, const __bf16* __restrict__ K, const __bf16* __restrict__ Vt,
    __bf16* __restrict__ Aout) {
    const int id = blockIdx.x;
    const int bh = id & 31;                 // XCD-pinned: id%8 == bh%8
    const int qt = 31 - (id >> 5);          // big tiles first
    const int b = bh >> 4, h = bh & 15;
    const int tid = threadIdx.x, lane = tid & 63, wave = tid >> 6;
    const int wq = wave >> 1, wk = wave & 1;
    const int l32 = lane & 31, hi = lane >> 5;

    __shared__ alignas(16) __bf16 SMEM[128 * 64 + 64 * 128];  // Ks | Vs (32 KB)
    __bf16* Ks = SMEM;
    __bf16* Vs = SMEM + 128 * 64;

    const size_t base = (size_t)bh * S_LEN * HDIM;   // same for Q, K, Vt
    const int q0 = qt * 64;
    const int q_lane = q0 + wq * 32 + l32;

    bf16x8 qf[4];
#pragma unroll
    for (int j = 0; j < 4; j++)
        qf[j] = *(const bf16x8*)&Q[base + (size_t)q_lane * HDIM + j * 16 + hi * 8];

    bf16x8 onesf;
#pragma unroll
    for (int jj = 0; jj < 8; jj++) onesf[jj] = (__bf16)1.0f;

    f32x16 oacc[2] = {};
    f32x16 lacc = {};

    // staging lane roles
    const int r8k = lane >> 3;
    const int sck = ((lane & 7) ^ r8k) * 8;   // K source chunk (elems)
    const int r4v = lane >> 4;                // V: 4 rows per glds

    const int kb_all = (qt >> 1) + 1;
    const int kl0 = wk * 64;                  // this wave's local k base

    for (int kb = 0; kb < kb_all; kb++) {
        const int k0 = kb * 128;
        __syncthreads();
#pragma unroll
        for (int p = 0; p < 4; p++) {  // K: 128 rows, 8 rows/glds
            const int row = wave * 32 + p * 8;
            __builtin_amdgcn_global_load_lds(
                (const AS1 void*)&K[base + (size_t)(k0 + row + r8k) * HDIM + sck],
                (AS3 void*)&Ks[row * 64], 16, 0, 0);
        }
#pragma unroll
        for (int p = 0; p < 4; p++) {  // V^T: 64 rows x 128 cols, 4 rows/glds
            const int row = wave * 16 + p * 4;
            const int lc = ((lane & 15) ^ ((p * 4 + r4v) & 15)) * 8;
            __builtin_amdgcn_global_load_lds(
                (const AS1 void*)&Vt[base + (size_t)(row + r4v) * S_LEN + k0 + lc],
                (AS3 void*)&Vs[row * 128], 16, 0, 0);
        }
        __syncthreads();

        if (kb == kb_all - 1)
            attn_tile32<true>(Ks, Vs, qf, onesf, oacc, lacc, q_lane, kl0, k0 + kl0, lane);
        else
            attn_tile32<false>(Ks, Vs, qf, onesf, oacc, lacc, q_lane, kl0, k0 + kl0, lane);
    }

    // ---- k-half reduction via LDS scratch (stride 49 f32: conflict-free) ----
    __syncthreads();
    float* scr = (float*)SMEM;
    const int slot = (wq * 64 + lane) * 49;
    if (wk) {
#pragma unroll
        for (int ss = 0; ss < 2; ss++)
#pragma unroll
            for (int r = 0; r < 16; r++) scr[slot + ss * 16 + r] = oacc[ss][r];
#pragma unroll
        for (int r = 0; r < 16; r++) scr[slot + 32 + r] = lacc[r];
    }
    __syncthreads();
    if (!wk) {
#pragma unroll
        for (int ss = 0; ss < 2; ss++)
#pragma unroll
            for (int r = 0; r < 16; r++) oacc[ss][r] += scr[slot + ss * 16 + r];
#pragma unroll
        for (int r = 0; r < 16; r++) lacc[r] += scr[slot + 32 + r];
        float rl[16];
#pragma unroll
        for (int r = 0; r < 16; r++) rl[r] = 1.0f / lacc[r];
#pragma unroll
        for (int ss = 0; ss < 2; ss++)
#pragma unroll
            for (int r = 0; r < 16; r++) {
                const int q = q0 + wq * 32 + (r & 3) + 8 * (r >> 2) + 4 * hi;
                Aout[(size_t)(b * S_LEN + q) * DMODEL + h * 64 + ss * 32 + l32] =
                    (__bf16)(oacc[ss][r] * rl[r]);
            }
    }
}

extern "C" void kernel_launch(void* const* d_in, const int* in_sizes, int n_in,
                              void* d_out, int out_size, void* d_ws, size_t ws_size,
                              hipStream_t stream) {
    const float* x  = (const float*)d_in[0];
    // d_in[1] = mask: causal triu, reproduced analytically
    const float* wq = (const float*)d_in[2];
    const float* bq = (const float*)d_in[3];
    const float* wk = (const float*)d_in[4];
    const float* bk = (const float*)d_in[5];
    const float* wv = (const float*)d_in[6];
    const float* bv = (const float*)d_in[7];
    const float* wo = (const float*)d_in[8];
    const float* bo = (const float*)d_in[9];
    float* out = (float*)d_out;

    char* ws = (char*)d_ws;
    __bf16* xb  = (__bf16*)(ws);                          // 8 MiB
    __bf16* wqT = (__bf16*)(ws + ((size_t)8  << 20));     // 2 MiB each
    __bf16* wkT = (__bf16*)(ws + ((size_t)10 << 20));
    __bf16* wvT = (__bf16*)(ws + ((size_t)12 << 20));
    __bf16* woT = (__bf16*)(ws + ((size_t)14 << 20));
    __bf16* Qb  = (__bf16*)(ws + ((size_t)16 << 20));     // 8 MiB each
    __bf16* Kb  = (__bf16*)(ws + ((size_t)24 << 20));
    __bf16* Vtb = (__bf16*)(ws + ((size_t)32 << 20));     // V^T [B,H,HD,S]
    __bf16* Ab  = (__bf16*)(ws + ((size_t)40 << 20));     // 8 MiB

    cast_x_kernel<<<4096, 256, 0, stream>>>(x, xb);
    transpose_cast_kernel<<<dim3(32, 32, 4), dim3(32, 8), 0, stream>>>(
        wq, wk, wv, wo, wqT, wkT, wvT, woT);
    gemm_qkv_kernel<<<dim3(64, 16), 256, 0, stream>>>(xb, wqT, wkT, wvT, bq, bk, bv, Qb, Kb, Vtb);
    attn_kernel<<<1024, 256, 0, stream>>>(Qb, Kb, Vtb, Ab);
    gemm_out_kernel<<<dim3(64, 16), 256, 0, stream>>>(Ab, woT, bo, out);
}

// Round 13
// 183.641 us; speedup vs baseline: 1.0813x; 1.0138x over previous
//
#include <hip/hip_runtime.h>
#include <hip/hip_bf16.h>

// MHA fwd: B=2, S=2048, D=1024, H=16, HD=64. fp32 in/out, bf16 MFMA internals.
// R23 = R8 (best verified 183.6us) + prep consolidation:
//  - cast_x + transpose_cast merged into ONE prep_kernel (z=0..3 transpose,
//    z=4 cast). Saves a launch + serialization of two independent 3-7us
//    kernels. R12 accounting: total = kernels(~108) + fill(42, harness) +
//    ~30us gaps -> attacking the gap/launch structure.
//  - qkv reverted to R8 128x64 @ (32,16,3) (R22 fusion regressed: X re-reads
//    were already L2 hits, FETCH never dropped; occupancy 26->21).
// attn: R8/R17 exact. gemm_out: R8 exact.

typedef __bf16 bf16x8 __attribute__((ext_vector_type(8)));
typedef __bf16 bf16x4 __attribute__((ext_vector_type(4)));
typedef __bf16 bf16x2 __attribute__((ext_vector_type(2)));
typedef float f32x4 __attribute__((ext_vector_type(4)));
typedef float f32x16 __attribute__((ext_vector_type(16)));
typedef unsigned int u32x4 __attribute__((ext_vector_type(4)));

#define S_LEN 2048
#define DMODEL 1024
#define NHEAD 16
#define HDIM 64
#define MROWS 4096  // B*S

#define AS1 __attribute__((address_space(1)))
#define AS3 __attribute__((address_space(3)))

#define QSCALE 0.18033688f  // 0.125 * log2e: scores come out in log2 units

// ---- prep: weight transpose+cast (z=0..3) and x cast (z=4), one dispatch ----
__global__ void prep_kernel(
    const float* __restrict__ X, __bf16* __restrict__ Xb,
    const float* __restrict__ W0, const float* __restrict__ W1,
    const float* __restrict__ W2, const float* __restrict__ W3,
    __bf16* __restrict__ T0, __bf16* __restrict__ T1,
    __bf16* __restrict__ T2, __bf16* __restrict__ T3) {
    __shared__ float tile[32][33];
    if (blockIdx.z == 4) {
        // cast: 1024 (x,y) blocks x 256 threads x 16 elems = 4.19M floats
        const int bid = blockIdx.y * 32 + blockIdx.x;
        const int tid = threadIdx.y * 32 + threadIdx.x;
        const int i = (bid * 256 + tid) * 16;
#pragma unroll
        for (int c = 0; c < 4; c++) {
            float4 f = *(const float4*)&X[i + c * 4];
            Xb[i + c * 4 + 0] = (__bf16)f.x;
            Xb[i + c * 4 + 1] = (__bf16)f.y;
            Xb[i + c * 4 + 2] = (__bf16)f.z;
            Xb[i + c * 4 + 3] = (__bf16)f.w;
        }
        return;
    }
    const float* W = (blockIdx.z == 0) ? W0 : (blockIdx.z == 1) ? W1 : (blockIdx.z == 2) ? W2 : W3;
    __bf16* WT = (blockIdx.z == 0) ? T0 : (blockIdx.z == 1) ? T1 : (blockIdx.z == 2) ? T2 : T3;
    int bx = blockIdx.x, by = blockIdx.y;
    int tx = threadIdx.x;
    for (int i = threadIdx.y; i < 32; i += 8)
        tile[i][tx] = W[(size_t)(by * 32 + i) * DMODEL + bx * 32 + tx];
    __syncthreads();
    for (int i = threadIdx.y; i < 32; i += 8)
        WT[(size_t)(bx * 32 + i) * DMODEL + by * 32 + tx] = (__bf16)tile[tx][i];
}

// ------------- GEMM QKV: 128x64 tile, BK=64, glds(16B) + XOR swizzle ---------
__global__ __launch_bounds__(256) void gemm_qkv_kernel(
    const __bf16* __restrict__ X,
    const __bf16* __restrict__ WqT, const __bf16* __restrict__ WkT, const __bf16* __restrict__ WvT,
    const float* __restrict__ bq, const float* __restrict__ bk, const float* __restrict__ bv,
    __bf16* __restrict__ Q, __bf16* __restrict__ K, __bf16* __restrict__ Vt) {
    const int which = blockIdx.z;
    const __bf16* Bt = (which == 0) ? WqT : (which == 1) ? WkT : WvT;
    const float* bias = (which == 0) ? bq : (which == 1) ? bk : bv;
    __bf16* Out = (which == 0) ? Q : (which == 1) ? K : Vt;

    __shared__ alignas(16) __bf16 As[128 * 64];
    __shared__ alignas(16) __bf16 Bs[64 * 64];

    const int tid = threadIdx.x;
    const int lane = tid & 63;
    const int wave = tid >> 6;
    const int wm = wave >> 1, wn = wave & 1;
    const int quad = lane >> 4;
    const int l16 = lane & 15;
    const int m0 = blockIdx.x * 128;   // m-tile on x (XCD locality)
    const int n0 = blockIdx.y * 64;
    const int r8 = lane >> 3;
    const int sc8 = ((lane & 7) ^ r8) * 8;
    const int gq0 = ((0 + quad) ^ (l16 & 7)) * 8;
    const int gq1 = ((4 + quad) ^ (l16 & 7)) * 8;

    f32x4 acc[4][2] = {};

    for (int k0 = 0; k0 < DMODEL; k0 += 64) {
        __syncthreads();
#pragma unroll
        for (int p = 0; p < 4; p++) {  // A: 128 rows
            const int row = wave * 32 + p * 8;
            __builtin_amdgcn_global_load_lds(
                (const AS1 void*)&X[(size_t)(m0 + row + r8) * DMODEL + k0 + sc8],
                (AS3 void*)&As[row * 64], 16, 0, 0);
        }
#pragma unroll
        for (int p = 0; p < 2; p++) {  // B: 64 rows
            const int row = wave * 16 + p * 8;
            __builtin_amdgcn_global_load_lds(
                (const AS1 void*)&Bt[(size_t)(n0 + row + r8) * DMODEL + k0 + sc8],
                (AS3 void*)&Bs[row * 64], 16, 0, 0);
        }
        __syncthreads();
#pragma unroll
        for (int ks = 0; ks < 2; ks++) {
            const int g = ks ? gq1 : gq0;
            bf16x8 af[4], bfr[2];
#pragma unroll
            for (int t = 0; t < 4; t++)
                af[t] = *(bf16x8*)&As[(wm * 64 + t * 16 + l16) * 64 + g];
#pragma unroll
            for (int t = 0; t < 2; t++)
                bfr[t] = *(bf16x8*)&Bs[(wn * 32 + t * 16 + l16) * 64 + g];
#pragma unroll
            for (int mt = 0; mt < 4; mt++)
#pragma unroll
                for (int nt = 0; nt < 2; nt++)
                    acc[mt][nt] = __builtin_amdgcn_mfma_f32_16x16x32_bf16(af[mt], bfr[nt], acc[mt][nt], 0, 0, 0);
        }
    }

    // C/D layout: col = lane&15, row = quad*4 + reg  [m89-verified]
#pragma unroll
    for (int mt = 0; mt < 4; mt++)
#pragma unroll
        for (int nt = 0; nt < 2; nt++) {
            const int n = n0 + wn * 32 + nt * 16 + l16;
            const float bn = bias[n];
            const int h = n >> 6, hd = n & 63;
            const int mbase = m0 + wm * 64 + mt * 16 + quad * 4;
            if (which == 2) {
                __bf16 pk[4];
#pragma unroll
                for (int r = 0; r < 4; r++) pk[r] = (__bf16)(acc[mt][nt][r] + bn);
                const int m = mbase;
                const int b = m >> 11, s = m & 2047;
                *(uint2*)&Out[(((size_t)(b * NHEAD + h) * HDIM + hd) * S_LEN) + s] = *(uint2*)pk;
            } else {
                const float sc = (which == 0) ? QSCALE : 1.0f;  // Q: fold 1/8 * log2e
#pragma unroll
                for (int r = 0; r < 4; r++) {
                    const int m = mbase + r;
                    const int b = m >> 11, s = m & 2047;
                    Out[(((size_t)(b * NHEAD + h) * S_LEN + s) * HDIM) + hd] =
                        (__bf16)((acc[mt][nt][r] + bn) * sc);
                }
            }
        }
}

// ------------- GEMM OUT: 64x64 tile, BK=64, grid (64,16): m-tile on x --------
__global__ __launch_bounds__(256) void gemm_out_kernel(
    const __bf16* __restrict__ A, const __bf16* __restrict__ Bt,
    const float* __restrict__ bias, float* __restrict__ Y) {
    __shared__ alignas(16) __bf16 As[64 * 64];
    __shared__ alignas(16) __bf16 Bs[64 * 64];

    const int tid = threadIdx.x;
    const int lane = tid & 63;
    const int wave = tid >> 6;
    const int wm = wave >> 1, wn = wave & 1;
    const int quad = lane >> 4;
    const int l16 = lane & 15;
    const int m0 = blockIdx.x * 64;    // m-tile on x (XCD locality)
    const int n0 = blockIdx.y * 64;
    const int r8 = lane >> 3;
    const int sc8 = ((lane & 7) ^ r8) * 8;
    const int gq0 = ((0 + quad) ^ (l16 & 7)) * 8;
    const int gq1 = ((4 + quad) ^ (l16 & 7)) * 8;

    f32x4 acc[2][2] = {};

    for (int k0 = 0; k0 < DMODEL; k0 += 64) {
        __syncthreads();
#pragma unroll
        for (int p = 0; p < 2; p++) {
            const int row = wave * 16 + p * 8;
            __builtin_amdgcn_global_load_lds(
                (const AS1 void*)&A[(size_t)(m0 + row + r8) * DMODEL + k0 + sc8],
                (AS3 void*)&As[row * 64], 16, 0, 0);
            __builtin_amdgcn_global_load_lds(
                (const AS1 void*)&Bt[(size_t)(n0 + row + r8) * DMODEL + k0 + sc8],
                (AS3 void*)&Bs[row * 64], 16, 0, 0);
        }
        __syncthreads();
#pragma unroll
        for (int ks = 0; ks < 2; ks++) {
            const int g = ks ? gq1 : gq0;
            bf16x8 af[2], bfr[2];
#pragma unroll
            for (int t = 0; t < 2; t++) {
                af[t]  = *(bf16x8*)&As[(wm * 32 + t * 16 + l16) * 64 + g];
                bfr[t] = *(bf16x8*)&Bs[(wn * 32 + t * 16 + l16) * 64 + g];
            }
#pragma unroll
            for (int mt = 0; mt < 2; mt++)
#pragma unroll
                for (int nt = 0; nt < 2; nt++)
                    acc[mt][nt] = __builtin_amdgcn_mfma_f32_16x16x32_bf16(af[mt], bfr[nt], acc[mt][nt], 0, 0, 0);
        }
    }

#pragma unroll
    for (int mt = 0; mt < 2; mt++)
#pragma unroll
        for (int nt = 0; nt < 2; nt++)
#pragma unroll
            for (int r = 0; r < 4; r++) {
                int m = m0 + wm * 32 + mt * 16 + quad * 4 + r;
                int n = n0 + wn * 32 + nt * 16 + l16;
                Y[(size_t)m * DMODEL + n] = acc[mt][nt][r] + bias[n];
            }
}

// -------- flash attention (R8/R17: 32x32x16 MFMA, in-register P) -------------
// Ks[128 k][64 hd] (chunk ^= row&7), Vs[64 hd][128 k] (chunk ^= hd&15).
// Wave (wq,wk): 32 q-rows x 64 k-cols. Swapped QK: sacc = mfma(K,Q) = S^T,
// lane = q-col (lane&31), 16 k-rows via (r&3)+8*(r>>2)+4*(lane>>5).
// PA frags assembled via bf16-pack + shfl_xor(32). O += mfma(PA, V);
// l += mfma(PA, ones). V chunks offset by k-half (kl0>>3).
// Epilogue: k-half partials reduced via LDS scratch (stride 49 f32).

static __device__ __forceinline__ unsigned pkbf2(float a, float b) {
    bf16x2 t;
    t[0] = (__bf16)a;
    t[1] = (__bf16)b;
    return __builtin_bit_cast(unsigned, t);
}

template <bool MASK>
__device__ __forceinline__ void attn_tile32(
    const __bf16* Ks, const __bf16* Vs,
    const bf16x8 (&qf)[4], const bf16x8& onesf,
    f32x16 (&oacc)[2], f32x16& lacc,
    int q_lane, int kl0, int kabs0, int lane) {
    const int l32 = lane & 31, hi = lane >> 5, l7 = lane & 7, l15 = lane & 15;
    const int cbase = kl0 >> 3;   // wave's V chunk base (0 or 8)
    bf16x8 pa[4];
#pragma unroll
    for (int sub = 0; sub < 2; sub++) {
        f32x16 s = {};
        const int row = kl0 + sub * 32 + l32;
#pragma unroll
        for (int j = 0; j < 4; j++) {
            const int ch = ((2 * j + hi) ^ l7) * 8;
            bf16x8 kf = *(const bf16x8*)&Ks[row * 64 + ch];
            s = __builtin_amdgcn_mfma_f32_32x32x16_bf16(kf, qf[j], s, 0, 0, 0);
        }
        float p[16];
#pragma unroll
        for (int r = 0; r < 16; r++) {
            const float e = __builtin_amdgcn_exp2f(s[r]);
            if (MASK) {
                const int kabs = kabs0 + sub * 32 + (r & 3) + 8 * (r >> 2) + 4 * hi;
                p[r] = (kabs > q_lane) ? 0.0f : e;
            } else {
                p[r] = e;
            }
        }
        const unsigned c0 = pkbf2(p[0], p[1]),   c1 = pkbf2(p[2], p[3]);
        const unsigned c2 = pkbf2(p[4], p[5]),   c3 = pkbf2(p[6], p[7]);
        const unsigned c4 = pkbf2(p[8], p[9]),   c5 = pkbf2(p[10], p[11]);
        const unsigned c6 = pkbf2(p[12], p[13]), c7 = pkbf2(p[14], p[15]);
        const unsigned sA0 = hi ? c0 : c2, sA1 = hi ? c1 : c3;
        const unsigned rA0 = __shfl_xor(sA0, 32, 64), rA1 = __shfl_xor(sA1, 32, 64);
        const unsigned sB0 = hi ? c4 : c6, sB1 = hi ? c5 : c7;
        const unsigned rB0 = __shfl_xor(sB0, 32, 64), rB1 = __shfl_xor(sB1, 32, 64);
        u32x4 wA, wB;
        if (hi) {
            wA[0] = rA0; wA[1] = rA1; wA[2] = c2; wA[3] = c3;
            wB[0] = rB0; wB[1] = rB1; wB[2] = c6; wB[3] = c7;
        } else {
            wA[0] = c0; wA[1] = c1; wA[2] = rA0; wA[3] = rA1;
            wB[0] = c4; wB[1] = c5; wB[2] = rB0; wB[3] = rB1;
        }
        pa[sub * 2]     = __builtin_bit_cast(bf16x8, wA);
        pa[sub * 2 + 1] = __builtin_bit_cast(bf16x8, wB);
    }
#pragma unroll
    for (int kblk = 0; kblk < 4; kblk++) {
#pragma unroll
        for (int dsub = 0; dsub < 2; dsub++) {
            const int hd = dsub * 32 + l32;
            const int ch = ((cbase + kblk * 2 + hi) ^ l15) * 8;
            bf16x8 vf = *(const bf16x8*)&Vs[hd * 128 + ch];
            oacc[dsub] = __builtin_amdgcn_mfma_f32_32x32x16_bf16(pa[kblk], vf, oacc[dsub], 0, 0, 0);
        }
        lacc = __builtin_amdgcn_mfma_f32_32x32x16_bf16(pa[kblk], onesf, lacc, 0, 0, 0);
    }
}

__global__ __launch_bounds__(256, 3) void attn_kernel(
    const __bf16* __restrict__ Q, const __bf16* __restrict__ K, const __bf16* __restrict__ Vt,
    __bf16* __restrict__ Aout) {
    const int id = blockIdx.x;
    const int bh = id & 31;                 // XCD-pinned: id%8 == bh%8
    const int qt = 31 - (id >> 5);          // big tiles first
    const int b = bh >> 4, h = bh & 15;
    const int tid = threadIdx.x, lane = tid & 63, wave = tid >> 6;
    const int wq = wave >> 1, wk = wave & 1;
    const int l32 = lane & 31, hi = lane >> 5;

    __shared__ alignas(16) __bf16 SMEM[128 * 64 + 64 * 128];  // Ks | Vs (32 KB)
    __bf16* Ks = SMEM;
    __bf16* Vs = SMEM + 128 * 64;

    const size_t base = (size_t)bh * S_LEN * HDIM;   // same for Q, K, Vt
    const int q0 = qt * 64;
    const int q_lane = q0 + wq * 32 + l32;

    bf16x8 qf[4];
#pragma unroll
    for (int j = 0; j < 4; j++)
        qf[j] = *(const bf16x8*)&Q[base + (size_t)q_lane * HDIM + j * 16 + hi * 8];

    bf16x8 onesf;
#pragma unroll
    for (int jj = 0; jj < 8; jj++) onesf[jj] = (__bf16)1.0f;

    f32x16 oacc[2] = {};
    f32x16 lacc = {};

    // staging lane roles
    const int r8k = lane >> 3;
    const int sck = ((lane & 7) ^ r8k) * 8;   // K source chunk (elems)
    const int r4v = lane >> 4;                // V: 4 rows per glds

    const int kb_all = (qt >> 1) + 1;
    const int kl0 = wk * 64;                  // this wave's local k base

    for (int kb = 0; kb < kb_all; kb++) {
        const int k0 = kb * 128;
        __syncthreads();
#pragma unroll
        for (int p = 0; p < 4; p++) {  // K: 128 rows, 8 rows/glds
            const int row = wave * 32 + p * 8;
            __builtin_amdgcn_global_load_lds(
                (const AS1 void*)&K[base + (size_t)(k0 + row + r8k) * HDIM + sck],
                (AS3 void*)&Ks[row * 64], 16, 0, 0);
        }
#pragma unroll
        for (int p = 0; p < 4; p++) {  // V^T: 64 rows x 128 cols, 4 rows/glds
            const int row = wave * 16 + p * 4;
            const int lc = ((lane & 15) ^ ((p * 4 + r4v) & 15)) * 8;
            __builtin_amdgcn_global_load_lds(
                (const AS1 void*)&Vt[base + (size_t)(row + r4v) * S_LEN + k0 + lc],
                (AS3 void*)&Vs[row * 128], 16, 0, 0);
        }
        __syncthreads();

        if (kb == kb_all - 1)
            attn_tile32<true>(Ks, Vs, qf, onesf, oacc, lacc, q_lane, kl0, k0 + kl0, lane);
        else
            attn_tile32<false>(Ks, Vs, qf, onesf, oacc, lacc, q_lane, kl0, k0 + kl0, lane);
    }

    // ---- k-half reduction via LDS scratch (stride 49 f32: conflict-free) ----
    __syncthreads();
    float* scr = (float*)SMEM;
    const int slot = (wq * 64 + lane) * 49;
    if (wk) {
#pragma unroll
        for (int ss = 0; ss < 2; ss++)
#pragma unroll
            for (int r = 0; r < 16; r++) scr[slot + ss * 16 + r] = oacc[ss][r];
#pragma unroll
        for (int r = 0; r < 16; r++) scr[slot + 32 + r] = lacc[r];
    }
    __syncthreads();
    if (!wk) {
#pragma unroll
        for (int ss = 0; ss < 2; ss++)
#pragma unroll
            for (int r = 0; r < 16; r++) oacc[ss][r] += scr[slot + ss * 16 + r];
#pragma unroll
        for (int r = 0; r < 16; r++) lacc[r] += scr[slot + 32 + r];
        float rl[16];
#pragma unroll
        for (int r = 0; r < 16; r++) rl[r] = 1.0f / lacc[r];
#pragma unroll
        for (int ss = 0; ss < 2; ss++)
#pragma unroll
            for (int r = 0; r < 16; r++) {
                const int q = q0 + wq * 32 + (r & 3) + 8 * (r >> 2) + 4 * hi;
                Aout[(size_t)(b * S_LEN + q) * DMODEL + h * 64 + ss * 32 + l32] =
                    (__bf16)(oacc[ss][r] * rl[r]);
            }
    }
}

extern "C" void kernel_launch(void* const* d_in, const int* in_sizes, int n_in,
                              void* d_out, int out_size, void* d_ws, size_t ws_size,
                              hipStream_t stream) {
    const float* x  = (const float*)d_in[0];
    // d_in[1] = mask: causal triu, reproduced analytically
    const float* wq = (const float*)d_in[2];
    const float* bq = (const float*)d_in[3];
    const float* wk = (const float*)d_in[4];
    const float* bk = (const float*)d_in[5];
    const float* wv = (const float*)d_in[6];
    const float* bv = (const float*)d_in[7];
    const float* wo = (const float*)d_in[8];
    const float* bo = (const float*)d_in[9];
    float* out = (float*)d_out;

    char* ws = (char*)d_ws;
    __bf16* xb  = (__bf16*)(ws);                          // 8 MiB
    __bf16* wqT = (__bf16*)(ws + ((size_t)8  << 20));     // 2 MiB each
    __bf16* wkT = (__bf16*)(ws + ((size_t)10 << 20));
    __bf16* wvT = (__bf16*)(ws + ((size_t)12 << 20));
    __bf16* woT = (__bf16*)(ws + ((size_t)14 << 20));
    __bf16* Qb  = (__bf16*)(ws + ((size_t)16 << 20));     // 8 MiB each
    __bf16* Kb  = (__bf16*)(ws + ((size_t)24 << 20));
    __bf16* Vtb = (__bf16*)(ws + ((size_t)32 << 20));     // V^T [B,H,HD,S]
    __bf16* Ab  = (__bf16*)(ws + ((size_t)40 << 20));     // 8 MiB

    prep_kernel<<<dim3(32, 32, 5), dim3(32, 8), 0, stream>>>(
        x, xb, wq, wk, wv, wo, wqT, wkT, wvT, woT);
    gemm_qkv_kernel<<<dim3(32, 16, 3), 256, 0, stream>>>(xb, wqT, wkT, wvT, bq, bk, bv, Qb, Kb, Vtb);
    attn_kernel<<<1024, 256, 0, stream>>>(Qb, Kb, Vtb, Ab);
    gemm_out_kernel<<<dim3(64, 16), 256, 0, stream>>>(Ab, woT, bo, out);
}